// Round 2
// baseline (193.504 us; speedup 1.0000x reference)
//
#include <hip/hip_runtime.h>

// Sinkhorn, B=8 N=1024 C=64, T=2, eps=0.1, 20 iters, scale=1e-3.
// Only batch 7 contributes (reference returns losses[-1]).
// Row/col normalization scan == diagonal scaling: P = diag(u) K diag(v),
// u = 1/(K v), v = 1/(K^T u), 20 rounds; loss = sum u_i K_ij v_j W_ij,
// W_ij = -0.1*log(K_ij).

static constexpr int N = 1024;
static constexpr int C = 64;

// Workspace layout (floats). Total 2,230,528 floats ~ 8.92 MB.
static constexpr int WS_XS = 0;             // softmax(y_s[7]/2) : 1024*64
static constexpr int WS_YS = 65536;         // softmax(y_t[7]/2) : 1024*64
static constexpr int WS_K  = 131072;        // K                 : 1024*1024
static constexpr int WS_KT = 1179648;       // K^T               : 1024*1024
static constexpr int WS_U  = 2228224;       // u : 1024
static constexpr int WS_V  = 2229248;       // v : 1024
static constexpr int WS_P  = 2230272;       // block partials : 256

__device__ __forceinline__ float wsum(float v) {
    #pragma unroll
    for (int o = 32; o > 0; o >>= 1) v += __shfl_down(v, o, 64);
    return v;
}
__device__ __forceinline__ float wmax(float v) {
    #pragma unroll
    for (int o = 32; o > 0; o >>= 1) v = fmaxf(v, __shfl_down(v, o, 64));
    return v;
}

// ---- 1: softmax over N axis (dim=1), batch 7. One block per column; 128 blocks.
__global__ void __launch_bounds__(256)
softmax_k(const float* __restrict__ ysrc, const float* __restrict__ ytrc,
          float* __restrict__ ws)
{
    __shared__ float sm[4];
    const int tid = threadIdx.x, bid = blockIdx.x;
    const int wid = tid >> 6, lane = tid & 63;
    const float* src = ((bid < C) ? ysrc : ytrc) + 7 * N * C;
    float* dst = ws + ((bid < C) ? WS_XS : WS_YS);
    const int c = bid & (C - 1);

    float vals[4];
    float m = -1e30f;
    #pragma unroll
    for (int q = 0; q < 4; ++q) {
        vals[q] = src[(q * 256 + tid) * C + c] * 0.5f;   // y / T, T = 2
        m = fmaxf(m, vals[q]);
    }
    m = wmax(m);
    if (lane == 0) sm[wid] = m;
    __syncthreads();
    m = fmaxf(fmaxf(sm[0], sm[1]), fmaxf(sm[2], sm[3]));
    float s = 0.f;
    #pragma unroll
    for (int q = 0; q < 4; ++q) { vals[q] = expf(vals[q] - m); s += vals[q]; }
    s = wsum(s);
    __syncthreads();                 // protect sm reuse
    if (lane == 0) sm[wid] = s;
    __syncthreads();
    s = sm[0] + sm[1] + sm[2] + sm[3];
    const float inv = 1.0f / s;
    #pragma unroll
    for (int q = 0; q < 4; ++q) dst[(q * 256 + tid) * C + c] = vals[q] * inv;
}

// ---- 2: K_ij = exp(-10 * sum_c |x_ic - y_jc|), plus K^T; 32x32 tiles, 4/block.
//        Blocks 0..3 additionally init v = 1.
__global__ void __launch_bounds__(256)
buildK_k(float* __restrict__ ws)
{
    __shared__ float smem[5184];   // sx 32*64 | sy 32*65 (+1 pad) | kt 32*33
    float* xs  = ws + WS_XS;
    float* ysm = ws + WS_YS;
    float* K   = ws + WS_K;
    float* KT  = ws + WS_KT;
    const int tid = threadIdx.x, bid = blockIdx.x;

    if (bid < 4) ws[WS_V + bid * 256 + tid] = 1.0f;   // v := 1

    float* sx = smem;
    float* sy = smem + 2048;
    float* kt = smem + 4128;
    #pragma unroll 1
    for (int t = 0; t < 4; ++t) {
        const int tt = bid * 4 + t;
        const int ti = tt >> 5, tj = tt & 31;
        __syncthreads();
        for (int k = tid; k < 2048; k += 256) sx[k] = xs[ti * 2048 + k];
        for (int k = tid; k < 2048; k += 256)
            sy[(k >> 6) * 65 + (k & 63)] = ysm[tj * 2048 + k];
        __syncthreads();
        float kv[4];
        #pragma unroll
        for (int q = 0; q < 4; ++q) {
            const int idx = q * 256 + tid;
            const int il = idx >> 5, jl = idx & 31;
            float a = 0.f;
            #pragma unroll
            for (int c = 0; c < 64; ++c)
                a += fabsf(sx[il * 64 + c] - sy[jl * 65 + c]);
            kv[q] = expf(-10.0f * a);                       // exp(-W/eps)
            K[(ti * 32 + il) * N + tj * 32 + jl] = kv[q];   // coalesced over jl
        }
        __syncthreads();
        #pragma unroll
        for (int q = 0; q < 4; ++q) {
            const int idx = q * 256 + tid;
            kt[(idx >> 5) * 33 + (idx & 31)] = kv[q];
        }
        __syncthreads();
        #pragma unroll
        for (int q = 0; q < 4; ++q) {
            const int idx = q * 256 + tid;
            const int jl = idx >> 5, il = idx & 31;
            KT[(tj * 32 + jl) * N + ti * 32 + il] = kt[il * 33 + jl];
        }
    }
}

// ---- 3a: u = 1 / (K v).  Wave per row; 256 blocks x 4 waves = 1024 rows.
__global__ void __launch_bounds__(256)
rownorm_k(float* __restrict__ ws)
{
    const int r = blockIdx.x * 4 + (threadIdx.x >> 6);
    const int lane = threadIdx.x & 63;
    const float4* Kr4 = (const float4*)(ws + WS_K + r * N);
    const float4* v4  = (const float4*)(ws + WS_V);
    float acc = 0.f;
    #pragma unroll
    for (int j = lane; j < 256; j += 64) {
        const float4 kk = Kr4[j]; const float4 vv = v4[j];
        acc += kk.x * vv.x + kk.y * vv.y + kk.z * vv.z + kk.w * vv.w;
    }
    acc = wsum(acc);
    if (lane == 0) ws[WS_U + r] = 1.0f / acc;
}

// ---- 3b: v = 1 / (K^T u)
__global__ void __launch_bounds__(256)
colnorm_k(float* __restrict__ ws)
{
    const int r = blockIdx.x * 4 + (threadIdx.x >> 6);
    const int lane = threadIdx.x & 63;
    const float4* Kr4 = (const float4*)(ws + WS_KT + r * N);
    const float4* u4  = (const float4*)(ws + WS_U);
    float acc = 0.f;
    #pragma unroll
    for (int j = lane; j < 256; j += 64) {
        const float4 kk = Kr4[j]; const float4 uu = u4[j];
        acc += kk.x * uu.x + kk.y * uu.y + kk.z * uu.z + kk.w * uu.w;
    }
    acc = wsum(acc);
    if (lane == 0) ws[WS_V + r] = 1.0f / acc;
}

// ---- 4a: per-block loss partials: partial[bid] = sum over 4 rows of
//          u_i * sum_j K_ij v_j log(K_ij)
__global__ void __launch_bounds__(256)
loss_partial_k(float* __restrict__ ws)
{
    __shared__ float sm[4];
    const int tid = threadIdx.x, bid = blockIdx.x;
    const int wid = tid >> 6, lane = tid & 63;
    const int r = bid * 4 + wid;
    const float* K = ws + WS_K;
    const float* v = ws + WS_V;
    float acc = 0.f;
    for (int j = lane; j < N; j += 64) {
        const float k = K[r * N + j];
        acc += k * v[j] * logf(k);
    }
    acc = wsum(acc);
    if (lane == 0) sm[wid] = ws[WS_U + r] * acc;
    __syncthreads();
    if (tid == 0) ws[WS_P + bid] = sm[0] + sm[1] + sm[2] + sm[3];
}

// ---- 4b: final: out = 1e-3 * sum_ij P*W = -1e-4 * sum(partials)
__global__ void __launch_bounds__(256)
loss_final_k(const float* __restrict__ ws, float* __restrict__ out)
{
    __shared__ float sm[4];
    const int tid = threadIdx.x;
    const int wid = tid >> 6, lane = tid & 63;
    float acc = ws[WS_P + tid];            // 256 partials, one per thread
    acc = wsum(acc);
    if (lane == 0) sm[wid] = acc;
    __syncthreads();
    if (tid == 0)
        out[0] = -1e-4f * (sm[0] + sm[1] + sm[2] + sm[3]);  // 1e-3 * (-0.1)
}

extern "C" void kernel_launch(void* const* d_in, const int* in_sizes, int n_in,
                              void* d_out, int out_size, void* d_ws, size_t ws_size,
                              hipStream_t stream) {
    const float* y_s = (const float*)d_in[0];
    const float* y_t = (const float*)d_in[1];
    float* out = (float*)d_out;
    float* ws  = (float*)d_ws;

    softmax_k<<<dim3(128), dim3(256), 0, stream>>>(y_s, y_t, ws);
    buildK_k<<<dim3(256), dim3(256), 0, stream>>>(ws);
    for (int it = 0; it < 20; ++it) {
        rownorm_k<<<dim3(256), dim3(256), 0, stream>>>(ws);
        colnorm_k<<<dim3(256), dim3(256), 0, stream>>>(ws);
    }
    loss_partial_k<<<dim3(256), dim3(256), 0, stream>>>(ws);
    loss_final_k<<<dim3(1), dim3(256), 0, stream>>>(ws, out);
}